// Round 1
// baseline (3386.794 us; speedup 1.0000x reference)
//
#include <hip/hip_runtime.h>

#define EDIM 64

// ---- degree count: deg[col[e]] += 1 ----
__global__ void k_deg(const int* __restrict__ col, float* __restrict__ deg, int E) {
    int e = blockIdx.x * blockDim.x + threadIdx.x;
    if (e < E) atomicAdd(&deg[col[e]], 1.0f);
}

// ---- dis = deg>0 ? rsqrt(deg) : 0  (in place) ----
__global__ void k_dis(float* __restrict__ deg, int N) {
    int n = blockIdx.x * blockDim.x + threadIdx.x;
    if (n < N) {
        float d = deg[n];
        deg[n] = (d > 0.0f) ? rsqrtf(d) : 0.0f;
    }
}

// ---- w[e] = dis[row[e]] * dis[col[e]] ----
__global__ void k_w(const int* __restrict__ row, const int* __restrict__ col,
                    const float* __restrict__ dis, float* __restrict__ w, int E) {
    int e = blockIdx.x * blockDim.x + threadIdx.x;
    if (e < E) w[e] = dis[row[e]] * dis[col[e]];
}

// ---- out = alpha[0] * emb  (float4 over N*16 elements) ----
__global__ void k_init(const float* __restrict__ x, const float* __restrict__ alpha,
                       float* __restrict__ out, int n4) {
    int i = blockIdx.x * blockDim.x + threadIdx.x;
    if (i < n4) {
        float a = alpha[0];
        float4 v = ((const float4*)x)[i];
        v.x *= a; v.y *= a; v.z *= a; v.w *= a;
        ((float4*)out)[i] = v;
    }
}

// ---- scatter: xn[col[e]][:] += w[e] * x[row[e]][:]  (16 threads/edge, float4 each) ----
__global__ void k_scatter(const int* __restrict__ row, const int* __restrict__ col,
                          const float* __restrict__ w, const float* __restrict__ x,
                          float* __restrict__ xn, int E) {
    int t = blockIdx.x * blockDim.x + threadIdx.x;
    int e = t >> 4;
    if (e >= E) return;
    int q = t & 15;
    int r = row[e];
    int c = col[e];
    float wv = w[e];
    float4 v = ((const float4*)(x + (size_t)r * EDIM))[q];
    float* dst = xn + (size_t)c * EDIM + q * 4;
    atomicAdd(dst + 0, wv * v.x);
    atomicAdd(dst + 1, wv * v.y);
    atomicAdd(dst + 2, wv * v.z);
    atomicAdd(dst + 3, wv * v.w);
}

// ---- out += alpha_l * xn  (float4) ----
__global__ void k_axpy(const float* __restrict__ xn, const float* __restrict__ alphaP,
                       float* __restrict__ out, int n4) {
    int i = blockIdx.x * blockDim.x + threadIdx.x;
    if (i < n4) {
        float a = alphaP[0];
        float4 v = ((const float4*)xn)[i];
        float4 o = ((float4*)out)[i];
        o.x += a * v.x; o.y += a * v.y; o.z += a * v.z; o.w += a * v.w;
        ((float4*)out)[i] = o;
    }
}

// ---- res[e] = dot(out[row[e]], out[col[e]])  (16 threads/edge, float4 each) ----
__global__ void k_dot(const int* __restrict__ row, const int* __restrict__ col,
                      const float* __restrict__ out, float* __restrict__ res, int E) {
    int t = blockIdx.x * blockDim.x + threadIdx.x;
    int e = t >> 4;
    if (e >= E) return;
    int q = t & 15;
    int r = row[e];
    int c = col[e];
    float4 a = ((const float4*)(out + (size_t)r * EDIM))[q];
    float4 b = ((const float4*)(out + (size_t)c * EDIM))[q];
    float s = a.x * b.x + a.y * b.y + a.z * b.z + a.w * b.w;
    s += __shfl_xor(s, 1, 16);
    s += __shfl_xor(s, 2, 16);
    s += __shfl_xor(s, 4, 16);
    s += __shfl_xor(s, 8, 16);
    if (q == 0) res[e] = s;
}

extern "C" void kernel_launch(void* const* d_in, const int* in_sizes, int n_in,
                              void* d_out, int out_size, void* d_ws, size_t ws_size,
                              hipStream_t stream) {
    const int*   edge  = (const int*)d_in[0];     // [2][E]
    const float* emb   = (const float*)d_in[1];   // [N][64]
    const float* alpha = (const float*)d_in[2];   // [4]
    float*       res   = (float*)d_out;           // [E]

    const int E = in_sizes[0] / 2;
    const int N = in_sizes[1] / EDIM;
    const int* row = edge;
    const int* col = edge + E;

    // workspace layout (floats)
    float* ws   = (float*)d_ws;
    float* deg  = ws;                       // N floats (reused as dis)
    float* w    = ws + (1 << 17);           // E floats
    float* xb0  = w + 1441792 - (1 << 17);  // start at float offset 1441792
    // simpler: recompute offsets explicitly
    {
        size_t off_w  = 1 << 17;            // 131072
        size_t off_x0 = off_w + 1441792 - (1 << 17); // placeholder, fixed below
        (void)off_x0;
    }
    size_t off = (size_t)(1 << 17);
    w = ws + off;                 off += 1310720;      // E padded
    float* x0 = ws + off;         off += (size_t)N * EDIM;
    float* x1 = ws + off;         off += (size_t)N * EDIM;
    float* outb = ws + off;       off += (size_t)N * EDIM;
    (void)xb0; (void)ws_size;

    const int B = 256;
    const int n4 = N * (EDIM / 4);          // float4 elements of a feature matrix

    // 1. degree
    hipMemsetAsync(deg, 0, (size_t)N * sizeof(float), stream);
    k_deg<<<(E + B - 1) / B, B, 0, stream>>>(col, deg, E);
    // 2. dis (in place)
    k_dis<<<(N + B - 1) / B, B, 0, stream>>>(deg, N);
    // 3. edge weights
    k_w<<<(E + B - 1) / B, B, 0, stream>>>(row, col, deg, w, E);
    // 4. out = alpha0 * emb
    k_init<<<(n4 + B - 1) / B, B, 0, stream>>>(emb, alpha, outb, n4);

    // 5. three propagation layers
    const float* xcur = emb;
    float* xbuf[2] = {x0, x1};
    for (int l = 0; l < 3; ++l) {
        float* xn = xbuf[l & 1];
        hipMemsetAsync(xn, 0, (size_t)N * EDIM * sizeof(float), stream);
        k_scatter<<<((size_t)E * 16 + B - 1) / B, B, 0, stream>>>(row, col, w, xcur, xn, E);
        k_axpy<<<(n4 + B - 1) / B, B, 0, stream>>>(xn, alpha + l + 1, outb, n4);
        xcur = xn;
    }

    // 6. per-edge dot products
    k_dot<<<((size_t)E * 16 + B - 1) / B, B, 0, stream>>>(row, col, outb, res, E);
}

// Round 2
// 440.366 us; speedup vs baseline: 7.6909x; 7.6909x over previous
//
#include <hip/hip_runtime.h>

#define EDIM 64
#define SCAN_CHUNK 1024  // elements per scan block (256 thr x 4)

// ---- degree histogram over col (int atomics) ----
__global__ void k_deg(const int* __restrict__ col, int* __restrict__ deg, int E) {
    int e = blockIdx.x * blockDim.x + threadIdx.x;
    if (e < E) atomicAdd(&deg[col[e]], 1);
}

// ---- dis = deg>0 ? rsqrt(deg) : 0 ----
__global__ void k_dis(const int* __restrict__ deg, float* __restrict__ dis, int N) {
    int n = blockIdx.x * blockDim.x + threadIdx.x;
    if (n < N) {
        int d = deg[n];
        dis[n] = (d > 0) ? rsqrtf((float)d) : 0.0f;
    }
}

// ---- scan pass 1: per-block sums ----
__global__ void k_scan1(const int* __restrict__ deg, int* __restrict__ bsum, int N) {
    int tid = threadIdx.x;
    int n0 = blockIdx.x * SCAN_CHUNK + tid * 4;
    int s = 0;
    #pragma unroll
    for (int k = 0; k < 4; ++k) { int n = n0 + k; if (n < N) s += deg[n]; }
    for (int d = 1; d < 64; d <<= 1) s += __shfl_xor(s, d, 64);
    __shared__ int wsum[4];
    if ((tid & 63) == 0) wsum[tid >> 6] = s;
    __syncthreads();
    if (tid == 0) bsum[blockIdx.x] = wsum[0] + wsum[1] + wsum[2] + wsum[3];
}

// ---- scan pass 2: exclusive scan of bsum in place (nb <= 128) ----
__global__ void k_scan2(int* __restrict__ bsum, int nb) {
    int tid = threadIdx.x;                 // 128 threads
    int v = (tid < nb) ? bsum[tid] : 0;
    int lane = tid & 63;
    int inc = v;
    for (int d = 1; d < 64; d <<= 1) { int t = __shfl_up(inc, d, 64); if (lane >= d) inc += t; }
    __shared__ int ws0;
    if (tid == 63) ws0 = inc;
    __syncthreads();
    if (tid >= 64) inc += ws0;
    if (tid < nb) bsum[tid] = inc - v;     // exclusive
}

// ---- scan pass 3: full exclusive scan -> off, cur ----
__global__ void k_scan3(const int* __restrict__ deg, const int* __restrict__ boff,
                        int* __restrict__ off, int* __restrict__ cur, int N) {
    int tid = threadIdx.x;
    int n0 = blockIdx.x * SCAN_CHUNK + tid * 4;
    int vals[4]; int s = 0;
    #pragma unroll
    for (int k = 0; k < 4; ++k) { int n = n0 + k; int v = (n < N) ? deg[n] : 0; vals[k] = s; s += v; }
    int lane = tid & 63;
    int inc = s;
    for (int d = 1; d < 64; d <<= 1) { int t = __shfl_up(inc, d, 64); if (lane >= d) inc += t; }
    int excl = inc - s;
    __shared__ int wsum[4];
    if (lane == 63) wsum[tid >> 6] = inc;
    __syncthreads();
    int w = tid >> 6;
    int woff = 0;
    for (int i = 0; i < w; ++i) woff += wsum[i];
    int base = boff[blockIdx.x] + woff + excl;
    #pragma unroll
    for (int k = 0; k < 4; ++k) {
        int n = n0 + k;
        if (n < N) { off[n] = base + vals[k]; cur[n] = base + vals[k]; }
    }
}

// ---- bucket placement: rowp = row permuted into CSR-by-col order ----
__global__ void k_place(const int* __restrict__ row, const int* __restrict__ col,
                        int* __restrict__ cur, int* __restrict__ rowp, int E) {
    int e = blockIdx.x * blockDim.x + threadIdx.x;
    if (e < E) {
        int pos = atomicAdd(&cur[col[e]], 1);
        rowp[pos] = row[e];
    }
}

// ---- out = alpha0 * emb ----
__global__ void k_init(const float* __restrict__ x, const float* __restrict__ alpha,
                       float* __restrict__ out, int n4) {
    int i = blockIdx.x * blockDim.x + threadIdx.x;
    if (i < n4) {
        float a = alpha[0];
        float4 v = ((const float4*)x)[i];
        v.x *= a; v.y *= a; v.z *= a; v.w *= a;
        ((float4*)out)[i] = v;
    }
}

// ---- gather-propagate: one wave per node; fused out += alpha*xn ----
__global__ void k_prop(const int* __restrict__ off, const int* __restrict__ rowp,
                       const float* __restrict__ dis, const float* __restrict__ x,
                       float* __restrict__ xn, float* __restrict__ outb,
                       const float* __restrict__ alphaP, int N, int E) {
    int wid = (blockIdx.x * blockDim.x + threadIdx.x) >> 6;
    if (wid >= N) return;
    int lane = threadIdx.x & 63;
    int j0 = off[wid];
    int j1 = (wid == N - 1) ? E : off[wid + 1];
    float dc = dis[wid];
    float acc = 0.0f;
    int j = j0;
    for (; j + 4 <= j1; j += 4) {
        int r0 = rowp[j], r1 = rowp[j + 1], r2 = rowp[j + 2], r3 = rowp[j + 3];
        float w0 = dis[r0], w1 = dis[r1], w2 = dis[r2], w3 = dis[r3];
        float v0 = x[(size_t)r0 * EDIM + lane];
        float v1 = x[(size_t)r1 * EDIM + lane];
        float v2 = x[(size_t)r2 * EDIM + lane];
        float v3 = x[(size_t)r3 * EDIM + lane];
        acc += w0 * v0;
        acc += w1 * v1;
        acc += w2 * v2;
        acc += w3 * v3;
    }
    for (; j < j1; ++j) {
        int r = rowp[j];
        acc += dis[r] * x[(size_t)r * EDIM + lane];
    }
    acc *= dc;
    size_t i = (size_t)wid * EDIM + lane;
    xn[i] = acc;
    outb[i] += alphaP[0] * acc;
}

// ---- res[e] = dot(out[row[e]], out[col[e]]) (16 threads/edge, float4 each) ----
__global__ void k_dot(const int* __restrict__ row, const int* __restrict__ col,
                      const float* __restrict__ out, float* __restrict__ res, int E) {
    int t = blockIdx.x * blockDim.x + threadIdx.x;
    int e = t >> 4;
    if (e >= E) return;
    int q = t & 15;
    int r = row[e];
    int c = col[e];
    float4 a = ((const float4*)(out + (size_t)r * EDIM))[q];
    float4 b = ((const float4*)(out + (size_t)c * EDIM))[q];
    float s = a.x * b.x + a.y * b.y + a.z * b.z + a.w * b.w;
    s += __shfl_xor(s, 1, 16);
    s += __shfl_xor(s, 2, 16);
    s += __shfl_xor(s, 4, 16);
    s += __shfl_xor(s, 8, 16);
    if (q == 0) res[e] = s;
}

extern "C" void kernel_launch(void* const* d_in, const int* in_sizes, int n_in,
                              void* d_out, int out_size, void* d_ws, size_t ws_size,
                              hipStream_t stream) {
    const int*   edge  = (const int*)d_in[0];     // [2][E]
    const float* emb   = (const float*)d_in[1];   // [N][64]
    const float* alpha = (const float*)d_in[2];   // [4]
    float*       res   = (float*)d_out;           // [E]

    const int E = in_sizes[0] / 2;
    const int N = in_sizes[1] / EDIM;
    const int* row = edge;
    const int* col = edge + E;

    // workspace layout in 4-byte words
    size_t o = 0;
    int*   degi = (int*)d_ws + 0;        o += (size_t)N;        // N
    float* dis  = (float*)d_ws + o;      o += (size_t)N;        // N
    int*   offA = (int*)d_ws + o;        o += (size_t)N;        // N
    int*   cur  = (int*)d_ws + o;        o += (size_t)N;        // N
    int*   bsum = (int*)d_ws + o;        o += 256;              // block sums
    int*   rowp = (int*)d_ws + o;        o += (size_t)E;        // E
    o = (o + 63) & ~63ull;
    float* x0   = (float*)d_ws + o;      o += (size_t)N * EDIM;
    float* x1   = (float*)d_ws + o;      o += (size_t)N * EDIM;
    float* outb = (float*)d_ws + o;      o += (size_t)N * EDIM;
    (void)ws_size; (void)n_in;

    const int B = 256;
    const int n4 = N * (EDIM / 4);
    const int nb = (N + SCAN_CHUNK - 1) / SCAN_CHUNK;   // 98 for N=100k (<=128)

    // CSR build
    hipMemsetAsync(degi, 0, (size_t)N * sizeof(int), stream);
    k_deg  <<<(E + B - 1) / B, B, 0, stream>>>(col, degi, E);
    k_dis  <<<(N + B - 1) / B, B, 0, stream>>>(degi, dis, N);
    k_scan1<<<nb, B, 0, stream>>>(degi, bsum, N);
    k_scan2<<<1, 128, 0, stream>>>(bsum, nb);
    k_scan3<<<nb, B, 0, stream>>>(degi, bsum, offA, cur, N);
    k_place<<<(E + B - 1) / B, B, 0, stream>>>(row, col, cur, rowp, E);

    // out = alpha0 * emb
    k_init <<<(n4 + B - 1) / B, B, 0, stream>>>(emb, alpha, outb, n4);

    // three gather layers (fused axpy)
    const float* xcur = emb;
    float* xbuf[2] = {x0, x1};
    for (int l = 0; l < 3; ++l) {
        float* xn = xbuf[l & 1];
        k_prop<<<((size_t)N * 64 + B - 1) / B, B, 0, stream>>>(
            offA, rowp, dis, xcur, xn, outb, alpha + l + 1, N, E);
        xcur = xn;
    }

    // per-edge dots
    k_dot<<<((size_t)E * 16 + B - 1) / B, B, 0, stream>>>(row, col, outb, res, E);
}

// Round 3
// 305.491 us; speedup vs baseline: 11.0864x; 1.4415x over previous
//
#include <hip/hip_runtime.h>

#define EDIM 64
#define CHUNK 4096          // edges per Phase-A block
#define BSH 9               // bucket = col >> 9  (512 cols/bucket)
#define BCOLS 512
#define CAP 8192            // per-bucket pair capacity (avg ~6378, Poisson-safe)

// ---------- bf16 helpers (bit ops, RNE) ----------
__device__ __forceinline__ unsigned f2_to_bf2(float a, float b) {
    unsigned ua = __float_as_uint(a); ua += 0x7fffu + ((ua >> 16) & 1u);
    unsigned ub = __float_as_uint(b); ub += 0x7fffu + ((ub >> 16) & 1u);
    return (ua >> 16) | (ub & 0xffff0000u);
}
__device__ __forceinline__ float bf_lo(unsigned u) { return __uint_as_float(u << 16); }
__device__ __forceinline__ float bf_hi(unsigned u) { return __uint_as_float(u & 0xffff0000u); }

// ---------- emb (fp32) -> x16 (bf16) ----------
__global__ __launch_bounds__(256) void k_cvt_emb(const float* __restrict__ emb,
                                                 unsigned* __restrict__ x16, int n4) {
    int i = blockIdx.x * blockDim.x + threadIdx.x;   // one float4 -> one uint2
    if (i < n4) {
        float4 v = ((const float4*)emb)[i];
        uint2 o; o.x = f2_to_bf2(v.x, v.y); o.y = f2_to_bf2(v.z, v.w);
        ((uint2*)x16)[i] = o;
    }
}

// ---------- bucket cursor init: bcur[b] = b*CAP ----------
__global__ void k_binit(int* __restrict__ bcur, int nb) {
    int b = threadIdx.x;
    if (b < nb) bcur[b] = b * CAP;
}

// ---------- Phase A: LDS bucket-sort chunks, write coalesced runs of (row,col) ----------
__global__ __launch_bounds__(256) void k_binA(const int* __restrict__ row, const int* __restrict__ col,
                                              int* __restrict__ bcur, uint2* __restrict__ pairs,
                                              int E, int nb) {
    __shared__ uint2 buf[CHUNK];
    __shared__ int histL[256], baseL[256], curL[256], gbaseL[256];
    __shared__ int wsum[4];
    int tid = threadIdx.x;
    int c0 = blockIdx.x * CHUNK;
    int cend = min(CHUNK, E - c0);

    if (tid < 256) histL[tid] = 0;
    __syncthreads();

    // 1) histogram + keep edges in regs
    int myr[CHUNK / 256], myc[CHUNK / 256];
    #pragma unroll
    for (int k = 0; k < CHUNK / 256; ++k) {
        int i = k * 256 + tid;
        if (i < cend) {
            int e = c0 + i;
            myr[k] = row[e]; myc[k] = col[e];
            atomicAdd(&histL[myc[k] >> BSH], 1);
        }
    }
    __syncthreads();

    // 2) exclusive scan of histL over 256 threads
    int v = histL[tid];
    int lane = tid & 63, w = tid >> 6;
    int inc = v;
    #pragma unroll
    for (int d = 1; d < 64; d <<= 1) { int t = __shfl_up(inc, d, 64); if (lane >= d) inc += t; }
    if (lane == 63) wsum[w] = inc;
    __syncthreads();
    int woff = 0;
    for (int i = 0; i < w; ++i) woff += wsum[i];
    int excl = inc - v + woff;
    baseL[tid] = excl;
    curL[tid] = excl;
    // 3) reserve global run positions
    if (tid < nb) gbaseL[tid] = atomicAdd(&bcur[tid], v);
    __syncthreads();

    // 4) scatter into LDS by bucket
    #pragma unroll
    for (int k = 0; k < CHUNK / 256; ++k) {
        int i = k * 256 + tid;
        if (i < cend) {
            int b = myc[k] >> BSH;
            int pos = atomicAdd(&curL[b], 1);
            buf[pos] = make_uint2((unsigned)myr[k], (unsigned)myc[k]);
        }
    }
    __syncthreads();

    // 5) coalesced write-out in bucket-major order
    for (int i = tid; i < cend; i += 256) {
        uint2 p = buf[i];
        int b = (int)(p.y >> BSH);
        int dst = gbaseL[b] + (i - baseL[b]);
        pairs[dst] = p;
    }
}

// ---------- tiny scan: bbase = exclusive_scan(bcur[b] - b*CAP) ----------
__global__ void k_bscan(const int* __restrict__ bcur, int* __restrict__ bbase, int nb) {
    __shared__ int wsum[4];
    int tid = threadIdx.x;
    int v = (tid < nb) ? (bcur[tid] - tid * CAP) : 0;
    int lane = tid & 63, w = tid >> 6;
    int inc = v;
    #pragma unroll
    for (int d = 1; d < 64; d <<= 1) { int t = __shfl_up(inc, d, 64); if (lane >= d) inc += t; }
    if (lane == 63) wsum[w] = inc;
    __syncthreads();
    int woff = 0;
    for (int i = 0; i < w; ++i) woff += wsum[i];
    if (tid < nb) bbase[tid] = inc - v + woff;
}

// ---------- Phase B: per-bucket deg/off/dis + placement into rowp ----------
__global__ __launch_bounds__(256) void k_binB(const uint2* __restrict__ pairs,
                                              const int* __restrict__ bcur, const int* __restrict__ bbase,
                                              int* __restrict__ off, float* __restrict__ dis,
                                              int* __restrict__ rowp, int N) {
    __shared__ int degL[BCOLS];
    __shared__ int curL[BCOLS];
    __shared__ int wsum[4];
    int tid = threadIdx.x;
    int b = blockIdx.x;
    int base_in = b * CAP;
    int cnt = bcur[b] - base_in;
    int col0 = b << BSH;
    int ncols = min(BCOLS, N - col0);

    degL[tid] = 0; degL[tid + 256] = 0;
    __syncthreads();

    for (int i = tid; i < cnt; i += 256)
        atomicAdd(&degL[(int)pairs[base_in + i].y - col0], 1);
    __syncthreads();

    // scan 512 deg values with 256 threads (2 elems each)
    int d0 = degL[2 * tid], d1 = degL[2 * tid + 1];
    int v = d0 + d1;
    int lane = tid & 63, w = tid >> 6;
    int inc = v;
    #pragma unroll
    for (int d = 1; d < 64; d <<= 1) { int t = __shfl_up(inc, d, 64); if (lane >= d) inc += t; }
    if (lane == 63) wsum[w] = inc;
    __syncthreads();
    int woff = 0;
    for (int i = 0; i < w; ++i) woff += wsum[i];
    int exclp = inc - v + woff + bbase[b];       // global exclusive offset of col 2*tid
    __syncthreads();                              // degL reads done before curL overlap writes
    int c0i = 2 * tid, c1i = 2 * tid + 1;
    if (c0i < ncols) {
        off[col0 + c0i] = exclp;
        dis[col0 + c0i] = (d0 > 0) ? rsqrtf((float)d0) : 0.0f;
        curL[c0i] = exclp;
    }
    if (c1i < ncols) {
        off[col0 + c1i] = exclp + d0;
        dis[col0 + c1i] = (d1 > 0) ? rsqrtf((float)d1) : 0.0f;
        curL[c1i] = exclp + d0;
    }
    __syncthreads();

    for (int i = tid; i < cnt; i += 256) {
        uint2 p = pairs[base_in + i];
        int pos = atomicAdd(&curL[(int)p.y - col0], 1);
        rowp[pos] = (int)p.x;
    }
}

// ---------- out = alpha0 * emb (fp32) ----------
__global__ __launch_bounds__(256) void k_init(const float* __restrict__ x, const float* __restrict__ alpha,
                                              float* __restrict__ out, int n4) {
    int i = blockIdx.x * blockDim.x + threadIdx.x;
    if (i < n4) {
        float a = alpha[0];
        float4 v = ((const float4*)x)[i];
        v.x *= a; v.y *= a; v.z *= a; v.w *= a;
        ((float4*)out)[i] = v;
    }
}

// ---------- gather-propagate: one wave per node, 2 edges in flight via half-waves ----------
__global__ __launch_bounds__(256) void k_prop(const int* __restrict__ off, const int* __restrict__ rowp,
                                              const float* __restrict__ dis,
                                              const unsigned short* __restrict__ x16,
                                              unsigned short* __restrict__ xn16,
                                              float* __restrict__ outb,
                                              unsigned short* __restrict__ outb16,
                                              const float* __restrict__ alphaP,
                                              int N, int E, int last) {
    int wid = (blockIdx.x * blockDim.x + threadIdx.x) >> 6;
    if (wid >= N) return;
    int lane = threadIdx.x & 63;
    int h = lane >> 5;           // which edge of the pair
    int s = lane & 31;           // dim pair index: dims 2s, 2s+1
    int j0 = off[wid];
    int j1 = (wid == N - 1) ? E : off[wid + 1];
    float dc = dis[wid];
    float a = alphaP[0];
    float ax = 0.0f, ay = 0.0f;

    int jj = j0 + h;
    for (; jj + 2 < j1; jj += 4) {
        int r0 = rowp[jj], r1 = rowp[jj + 2];
        float w0 = dis[r0], w1 = dis[r1];
        unsigned v0 = *(const unsigned*)(x16 + ((size_t)r0 << 6) + (s << 1));
        unsigned v1 = *(const unsigned*)(x16 + ((size_t)r1 << 6) + (s << 1));
        ax += w0 * bf_lo(v0); ay += w0 * bf_hi(v0);
        ax += w1 * bf_lo(v1); ay += w1 * bf_hi(v1);
    }
    for (; jj < j1; jj += 2) {
        int r = rowp[jj];
        float wv = dis[r];
        unsigned v = *(const unsigned*)(x16 + ((size_t)r << 6) + (s << 1));
        ax += wv * bf_lo(v); ay += wv * bf_hi(v);
    }

    ax += __shfl_xor(ax, 32, 64);
    ay += __shfl_xor(ay, 32, 64);

    if (h == 0) {
        ax *= dc; ay *= dc;
        size_t oi = ((size_t)wid << 6) + (s << 1);
        if (!last) *(unsigned*)(xn16 + oi) = f2_to_bf2(ax, ay);
        float2 o = *(float2*)(outb + oi);
        o.x += a * ax; o.y += a * ay;
        *(float2*)(outb + oi) = o;
        if (last) *(unsigned*)(outb16 + oi) = f2_to_bf2(o.x, o.y);
    }
}

// ---------- res[e] = dot(out16[row[e]], out16[col[e]]) : 16 lanes/edge, 4 dims/lane ----------
__global__ __launch_bounds__(256) void k_dot(const int* __restrict__ row, const int* __restrict__ col,
                                             const unsigned short* __restrict__ out16,
                                             float* __restrict__ res, int E) {
    int t = blockIdx.x * blockDim.x + threadIdx.x;
    int e = t >> 4;
    if (e >= E) return;
    int q = t & 15;
    int r = row[e];
    int c = col[e];
    uint2 av = *(const uint2*)(out16 + ((size_t)r << 6) + (q << 2));
    uint2 bv = *(const uint2*)(out16 + ((size_t)c << 6) + (q << 2));
    float s = bf_lo(av.x) * bf_lo(bv.x) + bf_hi(av.x) * bf_hi(bv.x)
            + bf_lo(av.y) * bf_lo(bv.y) + bf_hi(av.y) * bf_hi(bv.y);
    s += __shfl_xor(s, 1, 16);
    s += __shfl_xor(s, 2, 16);
    s += __shfl_xor(s, 4, 16);
    s += __shfl_xor(s, 8, 16);
    if (q == 0) res[e] = s;
}

extern "C" void kernel_launch(void* const* d_in, const int* in_sizes, int n_in,
                              void* d_out, int out_size, void* d_ws, size_t ws_size,
                              hipStream_t stream) {
    const int*   edge  = (const int*)d_in[0];     // [2][E]
    const float* emb   = (const float*)d_in[1];   // [N][64]
    const float* alpha = (const float*)d_in[2];   // [4]
    float*       res   = (float*)d_out;           // [E]

    const int E = in_sizes[0] / 2;
    const int N = in_sizes[1] / EDIM;
    const int* row = edge;
    const int* col = edge + E;
    const int NB = (N + BCOLS - 1) >> BSH;        // 196 for N=100k

    // workspace layout (4B words)
    size_t o = 0;
    int*   offA   = (int*)d_ws + o;   o += (size_t)N;
    float* dis    = (float*)d_ws + o; o += (size_t)N;
    int*   bcur   = (int*)d_ws + o;   o += 256;
    int*   bbase  = (int*)d_ws + o;   o += 256;
    int*   rowp   = (int*)d_ws + o;   o += (size_t)E;
    unsigned short* x16a = (unsigned short*)((int*)d_ws + o); o += (size_t)N * 32;
    unsigned short* x16b = (unsigned short*)((int*)d_ws + o); o += (size_t)N * 32;
    float* outb   = (float*)d_ws + o; o += (size_t)N * 64;
    uint2* pairs  = (uint2*)((int*)d_ws + o);     // NB*CAP*2 words; aliased below
    unsigned short* outb16 = (unsigned short*)pairs;  // pairs dead before outb16 written
    (void)ws_size; (void)n_in;

    const int B = 256;
    const int n4 = N * (EDIM / 4);                // float4 count for a feature matrix

    // bf16 copy of embeddings
    k_cvt_emb<<<(n4 + B - 1) / B, B, 0, stream>>>(emb, (unsigned*)x16a, n4);

    // CSR build: bin -> scan -> place
    k_binit<<<1, 256, 0, stream>>>(bcur, NB);
    k_binA <<<(E + CHUNK - 1) / CHUNK, B, 0, stream>>>(row, col, bcur, pairs, E, NB);
    k_bscan<<<1, 256, 0, stream>>>(bcur, bbase, NB);
    k_binB <<<NB, B, 0, stream>>>(pairs, bcur, bbase, offA, dis, rowp, N);

    // out = alpha0 * emb (fp32, exact on the dominant term)
    k_init <<<(n4 + B - 1) / B, B, 0, stream>>>(emb, alpha, outb, n4);

    // three gather layers (fused axpy; last layer also emits bf16 out)
    unsigned short* xcur = x16a;
    unsigned short* xnxt = x16b;
    for (int l = 0; l < 3; ++l) {
        int last = (l == 2);
        k_prop<<<((size_t)N * 64 + B - 1) / B, B, 0, stream>>>(
            offA, rowp, dis, xcur, xnxt, outb, outb16, alpha + l + 1, N, E, last);
        unsigned short* t = xcur; xcur = xnxt; xnxt = t;
    }

    // per-edge dots on bf16 out
    k_dot<<<((size_t)E * 16 + B - 1) / B, B, 0, stream>>>(row, col, outb16, res, E);
}

// Round 4
// 290.660 us; speedup vs baseline: 11.6521x; 1.0510x over previous
//
#include <hip/hip_runtime.h>

#define EDIM 64
#define CHUNK 4096          // edges per Phase-A block
#define BSH 9               // bucket = col >> 9  (512 cols/bucket)
#define BCOLS 512
#define CAP 8192            // per-bucket pair capacity (avg ~6400, +22 sigma)

// ---------- bf16 helpers (bit ops, RNE) ----------
__device__ __forceinline__ unsigned f2_to_bf2(float a, float b) {
    unsigned ua = __float_as_uint(a); ua += 0x7fffu + ((ua >> 16) & 1u);
    unsigned ub = __float_as_uint(b); ub += 0x7fffu + ((ub >> 16) & 1u);
    return (ua >> 16) | (ub & 0xffff0000u);
}
__device__ __forceinline__ float bf_lo(unsigned u) { return __uint_as_float(u << 16); }
__device__ __forceinline__ float bf_hi(unsigned u) { return __uint_as_float(u & 0xffff0000u); }

// ---------- bucket cursor init ----------
__global__ void k_binit(int* __restrict__ bcur, int nb) {
    int b = threadIdx.x;
    if (b < nb) bcur[b] = b * CAP;
}

// ---------- Phase A: LDS bucket-sort chunks, coalesced runs of (row,col) ----------
__global__ __launch_bounds__(256) void k_binA(const int* __restrict__ row, const int* __restrict__ col,
                                              int* __restrict__ bcur, uint2* __restrict__ pairs,
                                              int E, int nb) {
    __shared__ uint2 buf[CHUNK];
    __shared__ int histL[256], baseL[256], curL[256], gbaseL[256];
    __shared__ int wsum[4];
    int tid = threadIdx.x;
    int c0 = blockIdx.x * CHUNK;
    int cend = min(CHUNK, E - c0);

    histL[tid] = 0;
    __syncthreads();

    int myr[CHUNK / 256], myc[CHUNK / 256];
    #pragma unroll
    for (int k = 0; k < CHUNK / 256; ++k) {
        int i = k * 256 + tid;
        if (i < cend) {
            int e = c0 + i;
            myr[k] = row[e]; myc[k] = col[e];
            atomicAdd(&histL[myc[k] >> BSH], 1);
        }
    }
    __syncthreads();

    int v = histL[tid];
    int lane = tid & 63, w = tid >> 6;
    int inc = v;
    #pragma unroll
    for (int d = 1; d < 64; d <<= 1) { int t = __shfl_up(inc, d, 64); if (lane >= d) inc += t; }
    if (lane == 63) wsum[w] = inc;
    __syncthreads();
    int woff = 0;
    for (int i = 0; i < w; ++i) woff += wsum[i];
    int excl = inc - v + woff;
    baseL[tid] = excl;
    curL[tid] = excl;
    if (tid < nb) gbaseL[tid] = atomicAdd(&bcur[tid], v);
    __syncthreads();

    #pragma unroll
    for (int k = 0; k < CHUNK / 256; ++k) {
        int i = k * 256 + tid;
        if (i < cend) {
            int b = myc[k] >> BSH;
            int pos = atomicAdd(&curL[b], 1);
            buf[pos] = make_uint2((unsigned)myr[k], (unsigned)myc[k]);
        }
    }
    __syncthreads();

    for (int i = tid; i < cend; i += 256) {
        uint2 p = buf[i];
        int b = (int)(p.y >> BSH);
        int dst = gbaseL[b] + (i - baseL[b]);
        pairs[dst] = p;
    }
}

// ---------- tiny scan over bucket counts ----------
__global__ void k_bscan(const int* __restrict__ bcur, int* __restrict__ bbase, int nb) {
    __shared__ int wsum[4];
    int tid = threadIdx.x;
    int v = (tid < nb) ? (bcur[tid] - tid * CAP) : 0;
    int lane = tid & 63, w = tid >> 6;
    int inc = v;
    #pragma unroll
    for (int d = 1; d < 64; d <<= 1) { int t = __shfl_up(inc, d, 64); if (lane >= d) inc += t; }
    if (lane == 63) wsum[w] = inc;
    __syncthreads();
    int woff = 0;
    for (int i = 0; i < w; ++i) woff += wsum[i];
    if (tid < nb) bbase[tid] = inc - v + woff;
}

// ---------- Phase B: per-bucket deg/off/dis/invd + placement ----------
__global__ __launch_bounds__(256) void k_binB(const uint2* __restrict__ pairs,
                                              const int* __restrict__ bcur, const int* __restrict__ bbase,
                                              int* __restrict__ off, float* __restrict__ dis,
                                              float* __restrict__ invd,
                                              int* __restrict__ rowp, int N) {
    __shared__ int degL[BCOLS];
    __shared__ int curL[BCOLS];
    __shared__ int wsum[4];
    int tid = threadIdx.x;
    int b = blockIdx.x;
    int base_in = b * CAP;
    int cnt = bcur[b] - base_in;
    int col0 = b << BSH;
    int ncols = min(BCOLS, N - col0);

    degL[tid] = 0; degL[tid + 256] = 0;
    __syncthreads();

    for (int i = tid; i < cnt; i += 256)
        atomicAdd(&degL[(int)pairs[base_in + i].y - col0], 1);
    __syncthreads();

    int d0 = degL[2 * tid], d1 = degL[2 * tid + 1];
    int v = d0 + d1;
    int lane = tid & 63, w = tid >> 6;
    int inc = v;
    #pragma unroll
    for (int d = 1; d < 64; d <<= 1) { int t = __shfl_up(inc, d, 64); if (lane >= d) inc += t; }
    if (lane == 63) wsum[w] = inc;
    __syncthreads();
    int woff = 0;
    for (int i = 0; i < w; ++i) woff += wsum[i];
    int exclp = inc - v + woff + bbase[b];
    __syncthreads();
    int c0i = 2 * tid, c1i = 2 * tid + 1;
    if (c0i < ncols) {
        off[col0 + c0i] = exclp;
        dis[col0 + c0i] = (d0 > 0) ? rsqrtf((float)d0) : 0.0f;
        invd[col0 + c0i] = (d0 > 0) ? sqrtf((float)d0) : 0.0f;
        curL[c0i] = exclp;
    }
    if (c1i < ncols) {
        off[col0 + c1i] = exclp + d0;
        dis[col0 + c1i] = (d1 > 0) ? rsqrtf((float)d1) : 0.0f;
        invd[col0 + c1i] = (d1 > 0) ? sqrtf((float)d1) : 0.0f;
        curL[c1i] = exclp + d0;
    }
    __syncthreads();

    for (int i = tid; i < cnt; i += 256) {
        uint2 p = pairs[base_in + i];
        int pos = atomicAdd(&curL[(int)p.y - col0], 1);
        rowp[pos] = (int)p.x;
    }
}

// ---------- y0 = bf16(dis[n] * emb[n][:]) ----------
__global__ __launch_bounds__(256) void k_cvty(const float* __restrict__ emb,
                                              const float* __restrict__ dis,
                                              unsigned* __restrict__ y0, int n16) {
    int i = blockIdx.x * blockDim.x + threadIdx.x;   // one float4 per thread
    if (i < n16) {
        float d = dis[i >> 4];
        float4 v = ((const float4*)emb)[i];
        uint2 o; o.x = f2_to_bf2(d * v.x, d * v.y); o.y = f2_to_bf2(d * v.z, d * v.w);
        ((uint2*)y0)[i] = o;
    }
}

// ---------- gather layer: acc = sum y_in[rowp[j]];  y_out = dis^2 * acc
//            last layer: out16 = bf16(a0*emb + invd*(a1*y1 + a2*y2) + a3*dis*acc) ----------
__global__ __launch_bounds__(256) void k_prop(const int* __restrict__ off, const int* __restrict__ rowp,
                                              const float* __restrict__ dis, const float* __restrict__ invd,
                                              const unsigned short* __restrict__ yin,
                                              unsigned short* __restrict__ yout,
                                              const float* __restrict__ emb,
                                              const unsigned short* __restrict__ y1,
                                              const unsigned short* __restrict__ y2,
                                              const float* __restrict__ alpha,
                                              unsigned short* __restrict__ out16,
                                              int N, int E, int last) {
    int wid = (blockIdx.x * blockDim.x + threadIdx.x) >> 6;
    if (wid >= N) return;
    int lane = threadIdx.x & 63;
    int h = lane >> 5;           // which edge of the pair
    int s = lane & 31;           // dim-pair index: dims 2s, 2s+1
    int j0 = off[wid];
    int j1 = (wid == N - 1) ? E : off[wid + 1];
    float ax = 0.0f, ay = 0.0f;

    int jj = j0 + h;
    for (; jj + 2 < j1; jj += 4) {
        int r0 = rowp[jj], r1 = rowp[jj + 2];
        unsigned v0 = *(const unsigned*)(yin + ((size_t)r0 << 6) + (s << 1));
        unsigned v1 = *(const unsigned*)(yin + ((size_t)r1 << 6) + (s << 1));
        ax += bf_lo(v0) + bf_lo(v1);
        ay += bf_hi(v0) + bf_hi(v1);
    }
    for (; jj < j1; jj += 2) {
        int r = rowp[jj];
        unsigned v = *(const unsigned*)(yin + ((size_t)r << 6) + (s << 1));
        ax += bf_lo(v); ay += bf_hi(v);
    }

    ax += __shfl_xor(ax, 32, 64);
    ay += __shfl_xor(ay, 32, 64);

    if (h == 0) {
        float d = dis[wid];
        size_t oi = ((size_t)wid << 6) + (s << 1);
        if (!last) {
            float sc = d * d;
            *(unsigned*)(yout + oi) = f2_to_bf2(sc * ax, sc * ay);
        } else {
            float iv = invd[wid];
            float a0 = alpha[0], a1 = alpha[1], a2 = alpha[2], a3 = alpha[3];
            float2 e = *(const float2*)(emb + oi);
            unsigned u1 = *(const unsigned*)(y1 + oi);
            unsigned u2 = *(const unsigned*)(y2 + oi);
            float ox = a0 * e.x + iv * (a1 * bf_lo(u1) + a2 * bf_lo(u2)) + a3 * d * ax;
            float oy = a0 * e.y + iv * (a1 * bf_hi(u1) + a2 * bf_hi(u2)) + a3 * d * ay;
            *(unsigned*)(out16 + oi) = f2_to_bf2(ox, oy);
        }
    }
}

// ---------- res[e] = dot(out16[row[e]], out16[col[e]]) ----------
__global__ __launch_bounds__(256) void k_dot(const int* __restrict__ row, const int* __restrict__ col,
                                             const unsigned short* __restrict__ out16,
                                             float* __restrict__ res, int E) {
    int t = blockIdx.x * blockDim.x + threadIdx.x;
    int e = t >> 4;
    if (e >= E) return;
    int q = t & 15;
    int r = row[e];
    int c = col[e];
    uint2 av = *(const uint2*)(out16 + ((size_t)r << 6) + (q << 2));
    uint2 bv = *(const uint2*)(out16 + ((size_t)c << 6) + (q << 2));
    float s = bf_lo(av.x) * bf_lo(bv.x) + bf_hi(av.x) * bf_hi(bv.x)
            + bf_lo(av.y) * bf_lo(bv.y) + bf_hi(av.y) * bf_hi(bv.y);
    s += __shfl_xor(s, 1, 16);
    s += __shfl_xor(s, 2, 16);
    s += __shfl_xor(s, 4, 16);
    s += __shfl_xor(s, 8, 16);
    if (q == 0) res[e] = s;
}

extern "C" void kernel_launch(void* const* d_in, const int* in_sizes, int n_in,
                              void* d_out, int out_size, void* d_ws, size_t ws_size,
                              hipStream_t stream) {
    const int*   edge  = (const int*)d_in[0];     // [2][E]
    const float* emb   = (const float*)d_in[1];   // [N][64]
    const float* alpha = (const float*)d_in[2];   // [4]
    float*       res   = (float*)d_out;           // [E]

    const int E = in_sizes[0] / 2;
    const int N = in_sizes[1] / EDIM;
    const int* row = edge;
    const int* col = edge + E;
    const int NB = (N + BCOLS - 1) >> BSH;        // 196 for N=100k

    // workspace layout (4B words)
    size_t o = 0;
    int*   offA  = (int*)d_ws + o;   o += (size_t)N;
    float* dis   = (float*)d_ws + o; o += (size_t)N;
    float* invd  = (float*)d_ws + o; o += (size_t)N;
    int*   bcur  = (int*)d_ws + o;   o += 256;
    int*   bbase = (int*)d_ws + o;   o += 256;
    int*   rowp  = (int*)d_ws + o;   o += (size_t)E;
    unsigned short* y0 = (unsigned short*)((int*)d_ws + o); o += (size_t)N * 32;
    unsigned short* y1 = (unsigned short*)((int*)d_ws + o); o += (size_t)N * 32;
    unsigned short* y2 = (unsigned short*)((int*)d_ws + o); o += (size_t)N * 32;
    uint2* pairs = (uint2*)((int*)d_ws + o);      // NB*CAP uint2
    unsigned short* out16 = (unsigned short*)pairs;  // pairs dead after k_binB
    (void)ws_size; (void)n_in;

    const int B = 256;
    const int n16 = N * 16;                       // float4 count of emb

    // CSR build: bin -> scan -> place (also emits dis/invd)
    k_binit<<<1, 256, 0, stream>>>(bcur, NB);
    k_binA <<<(E + CHUNK - 1) / CHUNK, B, 0, stream>>>(row, col, bcur, pairs, E, NB);
    k_bscan<<<1, 256, 0, stream>>>(bcur, bbase, NB);
    k_binB <<<NB, B, 0, stream>>>(pairs, bcur, bbase, offA, dis, invd, rowp, N);

    // y0 = bf16(dis * emb)
    k_cvty <<<(n16 + B - 1) / B, B, 0, stream>>>(emb, dis, (unsigned*)y0, n16);

    // three gather layers; last fuses the alpha-combine and emits out16
    k_prop<<<((size_t)N * 64 + B - 1) / B, B, 0, stream>>>(
        offA, rowp, dis, invd, y0, y1, emb, y1, y2, alpha, out16, N, E, 0);
    k_prop<<<((size_t)N * 64 + B - 1) / B, B, 0, stream>>>(
        offA, rowp, dis, invd, y1, y2, emb, y1, y2, alpha, out16, N, E, 0);
    k_prop<<<((size_t)N * 64 + B - 1) / B, B, 0, stream>>>(
        offA, rowp, dis, invd, y2, (unsigned short*)0, emb, y1, y2, alpha, out16, N, E, 1);

    // per-edge dots on bf16 out
    k_dot<<<((size_t)E * 16 + B - 1) / B, B, 0, stream>>>(row, col, out16, res, E);
}

// Round 5
// 257.102 us; speedup vs baseline: 13.1730x; 1.1305x over previous
//
#include <hip/hip_runtime.h>

#define EDIM 64
#define CHUNK 4096          // edges per Phase-A block
#define BSH 9               // bucket = col >> 9  (512 cols/bucket)
#define BCOLS 512
#define CAP 8192            // per-bucket pair capacity (avg ~6400, +22 sigma)

// ---------- bf16 helpers (bit ops, RNE) ----------
__device__ __forceinline__ unsigned f2_to_bf2(float a, float b) {
    unsigned ua = __float_as_uint(a); ua += 0x7fffu + ((ua >> 16) & 1u);
    unsigned ub = __float_as_uint(b); ub += 0x7fffu + ((ub >> 16) & 1u);
    return (ua >> 16) | (ub & 0xffff0000u);
}
__device__ __forceinline__ float bf_lo(unsigned u) { return __uint_as_float(u << 16); }
__device__ __forceinline__ float bf_hi(unsigned u) { return __uint_as_float(u & 0xffff0000u); }

// ---------- bucket cursor init ----------
__global__ void k_binit(int* __restrict__ bcur, int nb) {
    int b = threadIdx.x;
    if (b < nb) bcur[b] = b * CAP;
}

// ---------- Phase A: LDS bucket-sort chunks, coalesced runs ----------
// pairs.x = row | (bucket << 24)   -> masked to row-only on writeout
// pairs.y = (edge_id << 9) | (col & 511)
__global__ __launch_bounds__(256) void k_binA(const int* __restrict__ row, const int* __restrict__ col,
                                              int* __restrict__ bcur, uint2* __restrict__ pairs,
                                              int E, int nb) {
    __shared__ uint2 buf[CHUNK];
    __shared__ int histL[256], baseL[256], curL[256], gbaseL[256];
    __shared__ int wsum[4];
    int tid = threadIdx.x;
    int c0 = blockIdx.x * CHUNK;
    int cend = min(CHUNK, E - c0);

    histL[tid] = 0;
    __syncthreads();

    int myr[CHUNK / 256], myc[CHUNK / 256];
    #pragma unroll
    for (int k = 0; k < CHUNK / 256; ++k) {
        int i = k * 256 + tid;
        if (i < cend) {
            int e = c0 + i;
            myr[k] = row[e]; myc[k] = col[e];
            atomicAdd(&histL[myc[k] >> BSH], 1);
        }
    }
    __syncthreads();

    int v = histL[tid];
    int lane = tid & 63, w = tid >> 6;
    int inc = v;
    #pragma unroll
    for (int d = 1; d < 64; d <<= 1) { int t = __shfl_up(inc, d, 64); if (lane >= d) inc += t; }
    if (lane == 63) wsum[w] = inc;
    __syncthreads();
    int woff = 0;
    for (int i = 0; i < w; ++i) woff += wsum[i];
    int excl = inc - v + woff;
    baseL[tid] = excl;
    curL[tid] = excl;
    if (tid < nb) gbaseL[tid] = atomicAdd(&bcur[tid], v);
    __syncthreads();

    #pragma unroll
    for (int k = 0; k < CHUNK / 256; ++k) {
        int i = k * 256 + tid;
        if (i < cend) {
            int b = myc[k] >> BSH;
            int e = c0 + i;
            int pos = atomicAdd(&curL[b], 1);
            buf[pos] = make_uint2((unsigned)myr[k] | ((unsigned)b << 24),
                                  ((unsigned)e << 9) | ((unsigned)myc[k] & (BCOLS - 1)));
        }
    }
    __syncthreads();

    for (int i = tid; i < cend; i += 256) {
        uint2 p = buf[i];
        int b = (int)(p.x >> 24);
        int dst = gbaseL[b] + (i - baseL[b]);
        pairs[dst] = make_uint2(p.x & 0x00FFFFFFu, p.y);
    }
}

// ---------- tiny scan over bucket counts ----------
__global__ void k_bscan(const int* __restrict__ bcur, int* __restrict__ bbase, int nb) {
    __shared__ int wsum[4];
    int tid = threadIdx.x;
    int v = (tid < nb) ? (bcur[tid] - tid * CAP) : 0;
    int lane = tid & 63, w = tid >> 6;
    int inc = v;
    #pragma unroll
    for (int d = 1; d < 64; d <<= 1) { int t = __shfl_up(inc, d, 64); if (lane >= d) inc += t; }
    if (lane == 63) wsum[w] = inc;
    __syncthreads();
    int woff = 0;
    for (int i = 0; i < w; ++i) woff += wsum[i];
    if (tid < nb) bbase[tid] = inc - v + woff;
}

// ---------- Phase B: per-bucket deg/off/dis/invd + placement (rowp + eidx) ----------
__global__ __launch_bounds__(256) void k_binB(const uint2* __restrict__ pairs,
                                              const int* __restrict__ bcur, const int* __restrict__ bbase,
                                              int* __restrict__ off, float* __restrict__ dis,
                                              float* __restrict__ invd,
                                              int* __restrict__ rowp, int* __restrict__ eidx, int N) {
    __shared__ int degL[BCOLS];
    __shared__ int curL[BCOLS];
    __shared__ int wsum[4];
    int tid = threadIdx.x;
    int b = blockIdx.x;
    int base_in = b * CAP;
    int cnt = bcur[b] - base_in;
    int col0 = b << BSH;
    int ncols = min(BCOLS, N - col0);

    degL[tid] = 0; degL[tid + 256] = 0;
    __syncthreads();

    for (int i = tid; i < cnt; i += 256)
        atomicAdd(&degL[(int)(pairs[base_in + i].y & (BCOLS - 1))], 1);
    __syncthreads();

    int d0 = degL[2 * tid], d1 = degL[2 * tid + 1];
    int v = d0 + d1;
    int lane = tid & 63, w = tid >> 6;
    int inc = v;
    #pragma unroll
    for (int d = 1; d < 64; d <<= 1) { int t = __shfl_up(inc, d, 64); if (lane >= d) inc += t; }
    if (lane == 63) wsum[w] = inc;
    __syncthreads();
    int woff = 0;
    for (int i = 0; i < w; ++i) woff += wsum[i];
    int exclp = inc - v + woff + bbase[b];
    __syncthreads();
    int c0i = 2 * tid, c1i = 2 * tid + 1;
    if (c0i < ncols) {
        off[col0 + c0i] = exclp;
        dis[col0 + c0i] = (d0 > 0) ? rsqrtf((float)d0) : 0.0f;
        invd[col0 + c0i] = (d0 > 0) ? sqrtf((float)d0) : 0.0f;
        curL[c0i] = exclp;
    }
    if (c1i < ncols) {
        off[col0 + c1i] = exclp + d0;
        dis[col0 + c1i] = (d1 > 0) ? rsqrtf((float)d1) : 0.0f;
        invd[col0 + c1i] = (d1 > 0) ? sqrtf((float)d1) : 0.0f;
        curL[c1i] = exclp + d0;
    }
    __syncthreads();

    for (int i = tid; i < cnt; i += 256) {
        uint2 p = pairs[base_in + i];
        int pos = atomicAdd(&curL[(int)(p.y & (BCOLS - 1))], 1);
        rowp[pos] = (int)p.x;
        eidx[pos] = (int)(p.y >> 9);
    }
}

// ---------- y0 = bf16(dis[n] * emb[n][:]) ----------
__global__ __launch_bounds__(256) void k_cvty(const float* __restrict__ emb,
                                              const float* __restrict__ dis,
                                              unsigned* __restrict__ y0, int n16) {
    int i = blockIdx.x * blockDim.x + threadIdx.x;
    if (i < n16) {
        float d = dis[i >> 4];
        float4 v = ((const float4*)emb)[i];
        uint2 o; o.x = f2_to_bf2(d * v.x, d * v.y); o.y = f2_to_bf2(d * v.z, d * v.w);
        ((uint2*)y0)[i] = o;
    }
}

// ---------- gather layer (4 edges in flight per half-wave) ----------
__global__ __launch_bounds__(256) void k_prop(const int* __restrict__ off, const int* __restrict__ rowp,
                                              const float* __restrict__ dis, const float* __restrict__ invd,
                                              const unsigned short* __restrict__ yin,
                                              unsigned short* __restrict__ yout,
                                              const float* __restrict__ emb,
                                              const unsigned short* __restrict__ y1,
                                              const unsigned short* __restrict__ y2,
                                              const float* __restrict__ alpha,
                                              unsigned short* __restrict__ out16,
                                              int N, int E, int last) {
    int wid = (blockIdx.x * blockDim.x + threadIdx.x) >> 6;
    if (wid >= N) return;
    int lane = threadIdx.x & 63;
    int h = lane >> 5;           // which edge of the pair
    int s = lane & 31;           // dim-pair index: dims 2s, 2s+1
    int j0 = off[wid];
    int j1 = (wid == N - 1) ? E : off[wid + 1];
    float ax = 0.0f, ay = 0.0f;

    int jj = j0 + h;
    for (; jj + 6 < j1; jj += 8) {
        int r0 = rowp[jj], r1 = rowp[jj + 2], r2 = rowp[jj + 4], r3 = rowp[jj + 6];
        unsigned v0 = *(const unsigned*)(yin + ((size_t)r0 << 6) + (s << 1));
        unsigned v1 = *(const unsigned*)(yin + ((size_t)r1 << 6) + (s << 1));
        unsigned v2 = *(const unsigned*)(yin + ((size_t)r2 << 6) + (s << 1));
        unsigned v3 = *(const unsigned*)(yin + ((size_t)r3 << 6) + (s << 1));
        ax += bf_lo(v0) + bf_lo(v1) + bf_lo(v2) + bf_lo(v3);
        ay += bf_hi(v0) + bf_hi(v1) + bf_hi(v2) + bf_hi(v3);
    }
    for (; jj < j1; jj += 2) {
        int r = rowp[jj];
        unsigned v = *(const unsigned*)(yin + ((size_t)r << 6) + (s << 1));
        ax += bf_lo(v); ay += bf_hi(v);
    }

    ax += __shfl_xor(ax, 32, 64);
    ay += __shfl_xor(ay, 32, 64);

    if (h == 0) {
        float d = dis[wid];
        size_t oi = ((size_t)wid << 6) + (s << 1);
        if (!last) {
            float sc = d * d;
            *(unsigned*)(yout + oi) = f2_to_bf2(sc * ax, sc * ay);
        } else {
            float iv = invd[wid];
            float a0 = alpha[0], a1 = alpha[1], a2 = alpha[2], a3 = alpha[3];
            float2 e = *(const float2*)(emb + oi);
            unsigned u1 = *(const unsigned*)(y1 + oi);
            unsigned u2 = *(const unsigned*)(y2 + oi);
            float ox = a0 * e.x + iv * (a1 * bf_lo(u1) + a2 * bf_lo(u2)) + a3 * d * ax;
            float oy = a0 * e.y + iv * (a1 * bf_hi(u1) + a2 * bf_hi(u2)) + a3 * d * ay;
            *(unsigned*)(out16 + oi) = f2_to_bf2(ox, oy);
        }
    }
}

// ---------- CSR-ordered dot: one wave per col node; col operand register-cached ----------
__global__ __launch_bounds__(256) void k_dotc(const int* __restrict__ off, const int* __restrict__ rowp,
                                              const int* __restrict__ eidx,
                                              const unsigned short* __restrict__ out16,
                                              float* __restrict__ res, int N, int E) {
    int wid = (blockIdx.x * blockDim.x + threadIdx.x) >> 6;
    if (wid >= N) return;
    int lane = threadIdx.x & 63;
    int g = lane >> 4;           // edge group 0..3
    int q = lane & 15;           // dim-quad index: 4 shorts per lane
    int j0 = off[wid];
    int j1 = (wid == N - 1) ? E : off[wid + 1];

    // col-side operand, loaded once per wave
    uint2 bv = *(const uint2*)(out16 + ((size_t)wid << 6) + (q << 2));

    int j = j0 + g;
    for (; j + 4 < j1; j += 8) {
        int r0 = rowp[j],     e0 = eidx[j];
        int r1 = rowp[j + 4], e1 = eidx[j + 4];
        uint2 a0 = *(const uint2*)(out16 + ((size_t)r0 << 6) + (q << 2));
        uint2 a1 = *(const uint2*)(out16 + ((size_t)r1 << 6) + (q << 2));
        float t0 = bf_lo(a0.x) * bf_lo(bv.x) + bf_hi(a0.x) * bf_hi(bv.x)
                 + bf_lo(a0.y) * bf_lo(bv.y) + bf_hi(a0.y) * bf_hi(bv.y);
        float t1 = bf_lo(a1.x) * bf_lo(bv.x) + bf_hi(a1.x) * bf_hi(bv.x)
                 + bf_lo(a1.y) * bf_lo(bv.y) + bf_hi(a1.y) * bf_hi(bv.y);
        t0 += __shfl_xor(t0, 1, 16); t1 += __shfl_xor(t1, 1, 16);
        t0 += __shfl_xor(t0, 2, 16); t1 += __shfl_xor(t1, 2, 16);
        t0 += __shfl_xor(t0, 4, 16); t1 += __shfl_xor(t1, 4, 16);
        t0 += __shfl_xor(t0, 8, 16); t1 += __shfl_xor(t1, 8, 16);
        if (q == 0) { res[e0] = t0; res[e1] = t1; }
    }
    for (; j < j1; j += 4) {
        int r = rowp[j], e = eidx[j];
        uint2 av = *(const uint2*)(out16 + ((size_t)r << 6) + (q << 2));
        float s = bf_lo(av.x) * bf_lo(bv.x) + bf_hi(av.x) * bf_hi(bv.x)
                + bf_lo(av.y) * bf_lo(bv.y) + bf_hi(av.y) * bf_hi(bv.y);
        s += __shfl_xor(s, 1, 16);
        s += __shfl_xor(s, 2, 16);
        s += __shfl_xor(s, 4, 16);
        s += __shfl_xor(s, 8, 16);
        if (q == 0) res[e] = s;
    }
}

extern "C" void kernel_launch(void* const* d_in, const int* in_sizes, int n_in,
                              void* d_out, int out_size, void* d_ws, size_t ws_size,
                              hipStream_t stream) {
    const int*   edge  = (const int*)d_in[0];     // [2][E]
    const float* emb   = (const float*)d_in[1];   // [N][64]
    const float* alpha = (const float*)d_in[2];   // [4]
    float*       res   = (float*)d_out;           // [E]

    const int E = in_sizes[0] / 2;
    const int N = in_sizes[1] / EDIM;
    const int* row = edge;
    const int* col = edge + E;
    const int NB = (N + BCOLS - 1) >> BSH;        // 196 for N=100k

    // workspace layout (4B words)
    size_t o = 0;
    int*   offA  = (int*)d_ws + o;   o += (size_t)N;
    float* dis   = (float*)d_ws + o; o += (size_t)N;
    float* invd  = (float*)d_ws + o; o += (size_t)N;
    int*   bcur  = (int*)d_ws + o;   o += 256;
    int*   bbase = (int*)d_ws + o;   o += 256;
    int*   rowp  = (int*)d_ws + o;   o += (size_t)E;
    int*   eidx  = (int*)d_ws + o;   o += (size_t)E;
    unsigned short* y0 = (unsigned short*)((int*)d_ws + o); o += (size_t)N * 32;
    unsigned short* y1 = (unsigned short*)((int*)d_ws + o); o += (size_t)N * 32;
    unsigned short* y2 = (unsigned short*)((int*)d_ws + o); o += (size_t)N * 32;
    uint2* pairs = (uint2*)((int*)d_ws + o);      // NB*CAP uint2
    unsigned short* out16 = (unsigned short*)pairs;  // pairs dead after k_binB
    (void)ws_size; (void)n_in;

    const int B = 256;
    const int n16 = N * 16;                       // float4 count of emb

    // CSR build: bin -> scan -> place (emits dis/invd, rowp, eidx)
    k_binit<<<1, 256, 0, stream>>>(bcur, NB);
    k_binA <<<(E + CHUNK - 1) / CHUNK, B, 0, stream>>>(row, col, bcur, pairs, E, NB);
    k_bscan<<<1, 256, 0, stream>>>(bcur, bbase, NB);
    k_binB <<<NB, B, 0, stream>>>(pairs, bcur, bbase, offA, dis, invd, rowp, eidx, N);

    // y0 = bf16(dis * emb)
    k_cvty <<<(n16 + B - 1) / B, B, 0, stream>>>(emb, dis, (unsigned*)y0, n16);

    // three gather layers; last fuses the alpha-combine and emits out16
    k_prop<<<((size_t)N * 64 + B - 1) / B, B, 0, stream>>>(
        offA, rowp, dis, invd, y0, y1, emb, y1, y2, alpha, out16, N, E, 0);
    k_prop<<<((size_t)N * 64 + B - 1) / B, B, 0, stream>>>(
        offA, rowp, dis, invd, y1, y2, emb, y1, y2, alpha, out16, N, E, 0);
    k_prop<<<((size_t)N * 64 + B - 1) / B, B, 0, stream>>>(
        offA, rowp, dis, invd, y2, (unsigned short*)0, emb, y1, y2, alpha, out16, N, E, 1);

    // per-edge dots in CSR order (col operand register-cached)
    k_dotc<<<((size_t)N * 64 + B - 1) / B, B, 0, stream>>>(offA, rowp, eidx, out16, res, N, E);
}